// Round 22
// baseline (415.675 us; speedup 1.0000x reference)
//
#include <hip/hip_runtime.h>
#include <math.h>

#define B_   32
#define L_   2048
#define DSEQ 1024
#define DGLB 1024
#define H_   16
#define DK_  64
#define DV_  64
#define LT   64
#define NT   (L_/LT)      // 32
#define PSTRIDE 66        // m, s, y[64]

// Wc2 layout: [h][ks(32)][j(128)][e(32)] bf16; d = ks*32 + e
#define WC_KSTRIDE 4096            // 128*32 elems per k-step
#define WC_HSTRIDE 131072          // 32*4096 elems per head

#define AS1 __attribute__((address_space(1)))
#define AS3 __attribute__((address_space(3)))

using u16    = unsigned short;
using bf16x8 = __attribute__((ext_vector_type(8))) short;
using f32x4  = __attribute__((ext_vector_type(4))) float;

__device__ __forceinline__ u16 f2bf(float x) {
  union { float f; unsigned int u; } v; v.f = x;
  return (u16)((v.u + 0x7fffu + ((v.u >> 16) & 1u)) >> 16);   // RNE
}

__device__ __forceinline__ float tanh_fast(float x) {
  float e = __builtin_exp2f(x * 2.885390081777927f);   // 2*log2(e)
  return 1.f - 2.f/(e + 1.f);
}

__device__ __forceinline__ float erf_fast(float x) {
  float ax = fabsf(x);
  float t  = 1.f/(1.f + 0.3275911f*ax);
  float p  = t*(0.254829592f + t*(-0.284496736f + t*(1.421413741f +
             t*(-1.453152027f + t*1.061405429f))));
  float e  = __builtin_exp2f(-ax*ax*1.4426950408889634f);  // e^{-x^2}
  float r  = 1.f - p*e;
  return copysignf(r, x);
}

#define PHASE_BARRIER(N)                                   \
  do {                                                     \
    __builtin_amdgcn_sched_barrier(0);                     \
    asm volatile("s_waitcnt vmcnt(" #N ")" ::: "memory");  \
    __builtin_amdgcn_s_barrier();                          \
    __builtin_amdgcn_sched_barrier(0);                     \
  } while (0)

// Wc2[h][d>>5][j][d&31]: j<64 -> Wk[h,:,j], else Wv[h,:,j-64]
__global__ void pack_w_kernel(const float* __restrict__ Wk,
                              const float* __restrict__ Wv,
                              u16* __restrict__ Wc) {
  const int h = blockIdx.x, j = blockIdx.y;
  const float* src = (j < DK_) ? (Wk + (size_t)h*DSEQ*DK_ + j)
                               : (Wv + (size_t)h*DSEQ*DV_ + (j - DK_));
  u16* dst = Wc + (size_t)h*WC_HSTRIDE + (size_t)j*32;
  for (int d = threadIdx.x; d < DSEQ; d += blockDim.x)
    dst[(size_t)(d >> 5)*WC_KSTRIDE + (d & 31)] = f2bf(src[(size_t)d*64]);
}

// S (fp32) -> Sb (bf16), flat; 8-elem granules, coalesced
__global__ void s2bf_kernel(const float* __restrict__ S, u16* __restrict__ Sb) {
  const size_t G = (size_t)B_*L_*DSEQ/8;
  for (size_t i = (size_t)blockIdx.x*256 + threadIdx.x; i < G; i += (size_t)4096*256) {
    const float4* sp = (const float4*)(S + i*8);
    float4 v0 = sp[0], v1 = sp[1];
    bf16x8 wv;
    wv[0]=(short)f2bf(v0.x); wv[1]=(short)f2bf(v0.y);
    wv[2]=(short)f2bf(v0.z); wv[3]=(short)f2bf(v0.w);
    wv[4]=(short)f2bf(v1.x); wv[5]=(short)f2bf(v1.y);
    wv[6]=(short)f2bf(v1.z); wv[7]=(short)f2bf(v1.w);
    *(bf16x8*)(Sb + i*8) = wv;
  }
}

// Q[b][h][k] = tanh(sum_d X[b,d]*Wq[h,d,k]); grid (H, B/4), 256 thr.
// Coalesced (r17): threads (dd=tid>>6, k=tid&63); LDS reduce over dd.
__global__ void q_proj_kernel(const float* __restrict__ X,
                              const float* __restrict__ Wq,
                              float* __restrict__ Q) {
  __shared__ float red[4][4][64];   // [dd][bb][k]
  const int h = blockIdx.x, b0 = blockIdx.y*4;
  const int k = threadIdx.x & 63, dd = threadIdx.x >> 6;
  const float* w = Wq + (size_t)h*DGLB*DK_ + (size_t)dd*256*DK_ + k;
  float a0=0.f, a1=0.f, a2=0.f, a3=0.f;
  for (int d = 0; d < 256; ++d) {
    float wv = w[(size_t)d*DK_];
    a0 += X[(size_t)(b0+0)*DGLB + dd*256 + d]*wv;
    a1 += X[(size_t)(b0+1)*DGLB + dd*256 + d]*wv;
    a2 += X[(size_t)(b0+2)*DGLB + dd*256 + d]*wv;
    a3 += X[(size_t)(b0+3)*DGLB + dd*256 + d]*wv;
  }
  red[dd][0][k]=a0; red[dd][1][k]=a1; red[dd][2][k]=a2; red[dd][3][k]=a3;
  __syncthreads();
  if (dd == 0) {
    #pragma unroll
    for (int bb = 0; bb < 4; ++bb) {
      float s = red[0][bb][k]+red[1][bb][k]+red[2][bb][k]+red[3][bb][k];
      Q[((size_t)(b0+bb)*H_+h)*DK_+k] = tanhf(s);
    }
  }
}

// grid: 8192 linear blocks, 256 threads = 4 waves, 4 blocks/CU (r20).
// r18 pairing (FETCH 528->267 MB verified) + 2-buffer counted pipeline.
// LDS 2 x 16 KB = 33 KB/block -> 4 blocks/CU; launch_bounds(256,4) ->
// 128-reg cap; B prefetch distance 2 (bA,bB). Phase s computes buf[s&1],
// stage(s+1) issued at phase start; end-of-phase vmcnt(16).
// Epilogue: er[] staging array ELIMINATED (r20 spilled 21 MB at the
// 128-reg cap) — shuffles inlined into the weighted-sum loop.
template<int BF16SRC>
__global__ __launch_bounds__(256, 4) void fused_kernel(
    const float* __restrict__ S, const u16* __restrict__ Sb,
    const u16* __restrict__ Wc, const float* __restrict__ Q,
    float* __restrict__ part) {
  __shared__ u16   Slds[2*64*128];   // 2 x 16 KB, rows 256 B
  __shared__ float lpart[2][64];

  const int id   = blockIdx.x;
  const int xcd  = id & 7;
  const int jg   = xcd >> 1;         // head-group 0..3 (pairs 2jg, 2jg+1)
  const int cpar = xcd & 1;          // tile parity
  const int idx  = id >> 3;          // 0..1023
  const int psel = idx & 1;
  const int mm   = idx >> 1;         // 0..511
  const int pair = 2*jg + psel;      // 0..7
  const int tile = (((mm + (jg << 7)) & 511) << 1) | cpar;   // 0..1023
  const int t    = tile & (NT-1), b = tile >> 5;

  const int tid  = threadIdx.x;
  const int wave = tid >> 6, lane = tid & 63;
  const int lhi  = lane >> 4, llo = lane & 15;
  const int isV  = wave & 1,  hp  = wave >> 1;
  const int h    = pair*2 + hp;

  const u16* wb = Wc + (size_t)h*WC_HSTRIDE + (size_t)(isV*64 + llo)*32 + lhi*8;
  int arow[4];
  #pragma unroll
  for (int rt = 0; rt < 4; ++rt) arow[rt] = (rt*16 + llo)*256;  // bytes

  const u16*   Sv = Sb + ((size_t)b*L_ + (size_t)t*LT)*DSEQ;
  const float* Sf = S  + ((size_t)b*L_ + (size_t)t*LT)*DSEQ;

  // stage sub-tile (sub: 64 rows x 128 k = 16 KB) into buf[sub&1]
  auto stage_gl = [&](int sub) {
    const int bs = (sub & 1) * 8192;           // u16 offset (16 KB)
    const int ko = (sub & 7) * 128;
    #pragma unroll
    for (int it = 0; it < 4; ++it) {
      const int jj  = wave*4 + it;
      const int row = 4*jj + (lane >> 4);
      const int g   = (lane & 15) ^ (row & 15);
      const u16* gp = Sv + (size_t)row*DSEQ + ko + (g << 3);
      __builtin_amdgcn_global_load_lds(
          (const AS1 void*)gp, (AS3 void*)(Slds + bs + jj*512), 16, 0, 0);
    }
  };
  auto stage_reg = [&](int sub) {              // fp32 fallback
    const int bs = (sub & 1) * 16384;          // bytes
    const int ko = (sub & 7) * 128;
    #pragma unroll
    for (int it = 0; it < 4; ++it) {
      int f = it*256 + tid, row = f >> 4, q = f & 15;
      int g = q ^ (row & 15);
      const float4* sp = (const float4*)(Sf + (size_t)row*DSEQ + ko + g*8);
      float4 v0 = sp[0], v1 = sp[1];
      bf16x8 wv;
      wv[0]=(short)f2bf(v0.x); wv[1]=(short)f2bf(v0.y);
      wv[2]=(short)f2bf(v0.z); wv[3]=(short)f2bf(v0.w);
      wv[4]=(short)f2bf(v1.x); wv[5]=(short)f2bf(v1.y);
      wv[6]=(short)f2bf(v1.z); wv[7]=(short)f2bf(v1.w);
      *(bf16x8*)((char*)Slds + bs + row*256 + q*16) = wv;
    }
  };

  f32x4 acc[4][4];
  #pragma unroll
  for (int rt = 0; rt < 4; ++rt)
    #pragma unroll
    for (int cc = 0; cc < 4; ++cc) acc[rt][cc] = {0.f,0.f,0.f,0.f};

  // prologue: stage sub 0 (pinned first), then B init (steps 0,1)
  if (BF16SRC) {
    stage_gl(0);
    __builtin_amdgcn_sched_barrier(0);
  }
  bf16x8 bA[4], bB[4];
  #pragma unroll
  for (int cc = 0; cc < 4; ++cc) bA[cc] = *(const bf16x8*)(wb + (size_t)0*WC_KSTRIDE + cc*512);
  #pragma unroll
  for (int cc = 0; cc < 4; ++cc) bB[cc] = *(const bf16x8*)(wb + (size_t)1*WC_KSTRIDE + cc*512);
  const u16* wbp = wb + (size_t)2*WC_KSTRIDE;  // rolling refill pointer
  if (BF16SRC) PHASE_BARRIER(8);               // stage(0) done; B-init in flight

  // one k-step (32 elems): consume BUF (step s*4+kk), refill with step +2
#define KSTEP(BUF, kk)                                                        \
  do {                                                                        \
    const int colb = (((kk)*4 + lhi) ^ llo) << 4;                             \
    __builtin_amdgcn_s_setprio(1);                                            \
    _Pragma("unroll")                                                         \
    for (int rt = 0; rt < 4; ++rt) {                                          \
      bf16x8 af = *(const bf16x8*)(cb + arow[rt] + colb);                     \
      acc[rt][0] = __builtin_amdgcn_mfma_f32_16x16x32_bf16(af, BUF[0], acc[rt][0], 0,0,0); \
      acc[rt][1] = __builtin_amdgcn_mfma_f32_16x16x32_bf16(af, BUF[1], acc[rt][1], 0,0,0); \
      acc[rt][2] = __builtin_amdgcn_mfma_f32_16x16x32_bf16(af, BUF[2], acc[rt][2], 0,0,0); \
      acc[rt][3] = __builtin_amdgcn_mfma_f32_16x16x32_bf16(af, BUF[3], acc[rt][3], 0,0,0); \
    }                                                                         \
    __builtin_amdgcn_s_setprio(0);                                            \
    {                                                                         \
      _Pragma("unroll")                                                       \
      for (int cc = 0; cc < 4; ++cc)                                          \
        BUF[cc] = *(const bf16x8*)(wbp + cc*512);                             \
      wbp += ((s*4 + (kk) + 2) == 31) ? -(ptrdiff_t)(31*WC_KSTRIDE)           \
                                      : (ptrdiff_t)WC_KSTRIDE;                \
    }                                                                         \
  } while (0)

  #pragma unroll
  for (int s = 0; s < 8; ++s) {
    if (BF16SRC) {
      if (s < 7) { stage_gl(s + 1); __builtin_amdgcn_sched_barrier(0); }
    } else {
      stage_reg(s);
      __syncthreads();
    }
    const char* cb = (const char*)Slds + (s & 1)*16384;
    KSTEP(bA, 0); KSTEP(bB, 1); KSTEP(bA, 2); KSTEP(bB, 3);
    if (BF16SRC) {
      // ops issued after stage(s+1): this phase's 16 B refills -> allow 16
      if (s < 7) PHASE_BARRIER(16);
      // s == 7: the epilogue __syncthreads drains
    } else {
      __syncthreads();
    }
  }
#undef KSTEP

  if (!isV) {
    // K-proj: tanh, dot with Q over 64 k-cols, reduce -> logit per row
    const float* Qb = Q + ((size_t)b*H_ + h)*DK_;
    float q[4];
    #pragma unroll
    for (int cc = 0; cc < 4; ++cc) q[cc] = Qb[16*cc + llo];
    #pragma unroll
    for (int rt = 0; rt < 4; ++rt) {
      #pragma unroll
      for (int r = 0; r < 4; ++r) {
        float pl = q[0]*tanh_fast(acc[rt][0][r]) + q[1]*tanh_fast(acc[rt][1][r])
                 + q[2]*tanh_fast(acc[rt][2][r]) + q[3]*tanh_fast(acc[rt][3][r]);
        pl += __shfl_xor(pl, 1); pl += __shfl_xor(pl, 2);
        pl += __shfl_xor(pl, 4); pl += __shfl_xor(pl, 8);
        if (llo == 0) lpart[hp][rt*16 + lhi*4 + r] = pl;
      }
    }
  } else {
    // V-proj: gelu (erf via A&S 7.1.26) in place
    #pragma unroll
    for (int rt = 0; rt < 4; ++rt)
      #pragma unroll
      for (int cc = 0; cc < 4; ++cc)
        #pragma unroll
        for (int r = 0; r < 4; ++r) {
          float x = acc[rt][cc][r];
          acc[rt][cc][r] = 0.5f*x*(1.f + erf_fast(x*0.70710678118654752f));
        }
  }
  __syncthreads();

  if (isV) {
    // softmax stats over this tile's 64 rows (lane <-> row)
    float lg = lpart[hp][lane] * 0.125f;   // 1/sqrt(64)
    float mx = lg;
    #pragma unroll
    for (int mk = 1; mk < 64; mk <<= 1) mx = fmaxf(mx, __shfl_xor(mx, mk));
    float ev = __expf(lg - mx);
    float sv = ev;
    #pragma unroll
    for (int mk = 1; mk < 64; mk <<= 1) sv += __shfl_xor(sv, mk);

    // weighted sum with INLINED shuffles (no er[16] array -> no spill)
    float y0 = 0.f, y1 = 0.f, y2 = 0.f, y3 = 0.f;
    #pragma unroll
    for (int rt = 0; rt < 4; ++rt) {
      #pragma unroll
      for (int r = 0; r < 4; ++r) {
        float e = __shfl(ev, rt*16 + lhi*4 + r);
        y0 += e*acc[rt][0][r];
        y1 += e*acc[rt][1][r];
        y2 += e*acc[rt][2][r];
        y3 += e*acc[rt][3][r];
      }
    }
    y0 += __shfl_xor(y0, 16); y0 += __shfl_xor(y0, 32);
    y1 += __shfl_xor(y1, 16); y1 += __shfl_xor(y1, 32);
    y2 += __shfl_xor(y2, 16); y2 += __shfl_xor(y2, 32);
    y3 += __shfl_xor(y3, 16); y3 += __shfl_xor(y3, 32);

    float* pt = part + (((size_t)b*H_ + h)*NT + t)*PSTRIDE;
    if (lhi == 0) {
      pt[2 + llo]      = y0;
      pt[2 + 16 + llo] = y1;
      pt[2 + 32 + llo] = y2;
      pt[2 + 48 + llo] = y3;
    }
    if (lane == 0) { pt[0] = mx; pt[1] = sv; }
  }
}

// merge NT tile-partials per (b,h); grid (H, B), block 64
__global__ void finalize_kernel(const float* __restrict__ part,
                                float* __restrict__ out) {
  const int h = blockIdx.x, b = blockIdx.y, v = threadIdx.x;
  const float* p = part + ((size_t)b*H_ + h)*(size_t)NT*PSTRIDE;
  float M = -3.0e38f;
  for (int tt = 0; tt < NT; ++tt) M = fmaxf(M, p[tt*PSTRIDE]);
  float ss = 0.f, y = 0.f;
  for (int tt = 0; tt < NT; ++tt) {
    float w = expf(p[tt*PSTRIDE] - M);
    ss += w*p[tt*PSTRIDE + 1];
    y  += w*p[tt*PSTRIDE + 2 + v];
  }
  out[((size_t)b*H_ + h)*DV_ + v] = y/ss;
}

extern "C" void kernel_launch(void* const* d_in, const int* in_sizes, int n_in,
                              void* d_out, int out_size, void* d_ws, size_t ws_size,
                              hipStream_t stream) {
  const float* X  = (const float*)d_in[0];
  const float* S  = (const float*)d_in[1];
  const float* Wq = (const float*)d_in[2];
  const float* Wk = (const float*)d_in[3];
  const float* Wv = (const float*)d_in[4];
  float* out = (float*)d_out;

  char* ws = (char*)d_ws;
  u16*   Wc    = (u16*)ws;                              // 4 MiB
  float* Qbuf  = (float*)(ws + (4u<<20));               // 128 KiB
  float* part  = (float*)(ws + (4u<<20) + (128u<<10));  // ~4.3 MiB
  u16*   Sb    = (u16*)(ws + (16u<<20));                // 128 MiB (optional)
  const bool useBf = ws_size >= (144ull << 20);

  pack_w_kernel  <<<dim3(H_, 128),  256, 0, stream>>>(Wk, Wv, Wc);
  q_proj_kernel  <<<dim3(H_, B_/4), 256, 0, stream>>>(X, Wq, Qbuf);
  if (useBf) {
    s2bf_kernel       <<<dim3(4096), 256, 0, stream>>>(S, Sb);
    fused_kernel<1>   <<<dim3(8192), 256, 0, stream>>>(S, Sb, Wc, Qbuf, part);
  } else {
    fused_kernel<0>   <<<dim3(8192), 256, 0, stream>>>(S, Sb, Wc, Qbuf, part);
  }
  finalize_kernel<<<dim3(H_, B_),    64, 0, stream>>>(part, out);
}